// Round 13
// baseline (150.151 us; speedup 1.0000x reference)
//
#include <hip/hip_runtime.h>
#include <hip/hip_fp16.h>
#include <math.h>

#define N_NODES 10000
#define D 128
#define NCOPY 16

typedef unsigned int uint_t;
typedef __attribute__((ext_vector_type(8))) _Float16 f16x8;
typedef __attribute__((ext_vector_type(4))) float f32x4;

#define MFMA16(a, b, c) __builtin_amdgcn_mfma_f32_16x16x32_f16((a), (b), (c), 0, 0, 0)

__device__ inline uint_t pack_h2(float lo, float hi) {
    __half2 h = __floats2half2_rn(lo, hi);
    return *(uint_t*)&h;
}
__device__ inline void acc_h8(uint4 v, float4& aA, float4& aB) {
    float2 f;
    f = __half22float2(*(__half2*)&v.x); aA.x += f.x; aA.y += f.y;
    f = __half22float2(*(__half2*)&v.y); aA.z += f.x; aA.w += f.y;
    f = __half22float2(*(__half2*)&v.z); aB.x += f.x; aB.y += f.y;
    f = __half22float2(*(__half2*)&v.w); aB.z += f.x; aB.w += f.y;
}

// ---------------- prep: zero deg + fp16 mirror of x + W^T fp16 ----------------
__global__ void prep_kernel(const float* __restrict__ x, __half* __restrict__ xm,
                            const float* __restrict__ W1l, const float* __restrict__ W1r,
                            const float* __restrict__ W2l, const float* __restrict__ W2r,
                            const float* __restrict__ W3l, const float* __restrict__ W3r,
                            __half* __restrict__ WT,
                            uint4* __restrict__ degz, int n8, int nz16, int nwt) {
    int i = blockIdx.x * blockDim.x + threadIdx.x;
    if (i < nz16) degz[i] = make_uint4(0u, 0u, 0u, 0u);
    if (i < n8) {
        const float4* p = (const float4*)x + (size_t)i * 2;
        float4 a = p[0], b = p[1];
        uint4 o;
        o.x = pack_h2(a.x, a.y); o.y = pack_h2(a.z, a.w);
        o.z = pack_h2(b.x, b.y); o.w = pack_h2(b.z, b.w);
        ((uint4*)xm)[i] = o;
    }
    if (i < nwt) {
        int m = i >> 14, idx = i & 16383;
        int n = idx >> 7, k = idx & 127;
        const float* Wm = (m == 0) ? W1l : (m == 1) ? W1r : (m == 2) ? W2l
                        : (m == 3) ? W2r : (m == 4) ? W3l : W3r;
        WT[i] = __float2half_rn(Wm[k * D + n]);   // WT[m][n][k] = W[k][n]
    }
}

// ---------------- CSR build ----------------
// pass 1: replicated histogram, non-returning atomics (no pos array)
__global__ void deg_kernel(const int* __restrict__ dst, int E, int* __restrict__ degN) {
    int i = blockIdx.x * blockDim.x + threadIdx.x;
    if (i < E) {
        int c = blockIdx.x & (NCOPY - 1);
        atomicAdd(&degN[c * N_NODES + dst[i]], 1);
    }
}

__global__ void sumdeg_kernel(const int* __restrict__ degN, int* __restrict__ tot, int n) {
    int i = blockIdx.x * blockDim.x + threadIdx.x;
    if (i < n) {
        int s = 0;
#pragma unroll
        for (int c = 0; c < NCOPY; ++c) s += degN[c * N_NODES + i];
        tot[i] = s;
    }
}

// single-block scan with LDS-staged coalesced IO: tot[0..n) -> offsets[0..n]
#define SCAN_PER 10
#define SCAN_N 10240
__global__ __launch_bounds__(1024) void scan_kernel(const int* __restrict__ tot,
                                                    int* __restrict__ offsets, int n) {
    __shared__ int buf[SCAN_N];
    __shared__ int wsum[16];
    __shared__ int wpre[16];
    int tid = threadIdx.x;
    int lane = tid & 63, wid = tid >> 6;
#pragma unroll
    for (int q = 0; q < SCAN_PER; ++q) {
        int idx = q * 1024 + tid;
        buf[idx] = (idx < n) ? tot[idx] : 0;
    }
    __syncthreads();
    int base = tid * SCAN_PER;
    int loc[SCAN_PER];
    int s = 0;
#pragma unroll
    for (int q = 0; q < SCAN_PER; ++q) {
        s += buf[base + q];
        loc[q] = s;
    }
    int mysum = s;
#pragma unroll
    for (int off = 1; off < 64; off <<= 1) {
        int t = __shfl_up(s, off, 64);
        if (lane >= off) s += t;
    }
    if (lane == 63) wsum[wid] = s;
    __syncthreads();
    if (wid == 0 && lane < 16) {
        int v = wsum[lane];
        int ss = v;
#pragma unroll
        for (int off = 1; off < 16; off <<= 1) {
            int t = __shfl_up(ss, off, 16);
            if ((lane & 15) >= off) ss += t;
        }
        wpre[lane] = ss - v;
    }
    __syncthreads();
    int thread_excl = wpre[wid] + (s - mysum);
#pragma unroll
    for (int q = 0; q < SCAN_PER; ++q) buf[base + q] = thread_excl + loc[q];
    __syncthreads();
#pragma unroll
    for (int q = 0; q < SCAN_PER; ++q) {
        int idx = q * 1024 + tid;
        if (idx < n) offsets[idx + 1] = buf[idx];
    }
    if (tid == 0) offsets[0] = 0;
}

__global__ void baseN_kernel(const int* __restrict__ degN, const int* __restrict__ offsets,
                             int* __restrict__ baseN, int n) {
    int i = blockIdx.x * blockDim.x + threadIdx.x;
    if (i < n) {
        int run = offsets[i];
#pragma unroll
        for (int c = 0; c < NCOPY; ++c) {
            baseN[c * N_NODES + i] = run;
            run += degN[c * N_NODES + i];
        }
    }
}

// pass 2: scatter with baseN as cursor (returning atomic + store).
// Copy mapping MUST match deg_kernel's (blockIdx & 15, 256 thr/block).
__global__ void scatter_kernel(const int* __restrict__ src, const int* __restrict__ dst,
                               int E, int* __restrict__ baseN, int* __restrict__ csr_src) {
    int i = blockIdx.x * blockDim.x + threadIdx.x;
    if (i < E) {
        int c = blockIdx.x & (NCOPY - 1);
        int slot = atomicAdd(&baseN[c * N_NODES + dst[i]], 1);
        csr_src[slot] = src[i];
    }
}

// ---------------- aggregation (segment mean, fp16 gather -> fp16 mean) ----------------
// 256 threads per node: 16 edge-groups x 16 lanes; lane covers 8 features (16B).
__global__ __launch_bounds__(256) void aggregate_kernel(const __half* __restrict__ h16,
                                                        const int* __restrict__ offsets,
                                                        const int* __restrict__ csr_src,
                                                        __half* __restrict__ mean16) {
    __shared__ float tmp[3][16][8];
    int node = blockIdx.x;
    int tid = threadIdx.x;
    int g = tid >> 4;          // 0..15 edge group
    int fl = tid & 15;         // feature block (8 fp16 = 16B)
    int beg = offsets[node], end = offsets[node + 1];
    float4 aA = make_float4(0.f, 0.f, 0.f, 0.f);
    float4 aB = make_float4(0.f, 0.f, 0.f, 0.f);
    float4 cA = make_float4(0.f, 0.f, 0.f, 0.f);
    float4 cB = make_float4(0.f, 0.f, 0.f, 0.f);
    int e = beg + g;
    for (; e + 16 < end; e += 32) {
        int s0 = csr_src[e];
        int s1 = csr_src[e + 16];
        uint4 v0 = *(const uint4*)&h16[s0 * D + fl * 8];
        uint4 v1 = *(const uint4*)&h16[s1 * D + fl * 8];
        acc_h8(v0, aA, aB);
        acc_h8(v1, cA, cB);
    }
    if (e < end) {
        int s0 = csr_src[e];
        uint4 v0 = *(const uint4*)&h16[s0 * D + fl * 8];
        acc_h8(v0, aA, aB);
    }
    aA.x += cA.x; aA.y += cA.y; aA.z += cA.z; aA.w += cA.w;
    aB.x += cB.x; aB.y += cB.y; aB.z += cB.z; aB.w += cB.w;
    aA.x += __shfl_xor(aA.x, 16, 64); aA.y += __shfl_xor(aA.y, 16, 64);
    aA.z += __shfl_xor(aA.z, 16, 64); aA.w += __shfl_xor(aA.w, 16, 64);
    aB.x += __shfl_xor(aB.x, 16, 64); aB.y += __shfl_xor(aB.y, 16, 64);
    aB.z += __shfl_xor(aB.z, 16, 64); aB.w += __shfl_xor(aB.w, 16, 64);
    aA.x += __shfl_xor(aA.x, 32, 64); aA.y += __shfl_xor(aA.y, 32, 64);
    aA.z += __shfl_xor(aA.z, 32, 64); aA.w += __shfl_xor(aA.w, 32, 64);
    aB.x += __shfl_xor(aB.x, 32, 64); aB.y += __shfl_xor(aB.y, 32, 64);
    aB.z += __shfl_xor(aB.z, 32, 64); aB.w += __shfl_xor(aB.w, 32, 64);
    int wv = tid >> 6;
    int lane = tid & 63;
    if (wv > 0 && lane < 16) {
        *(float4*)&tmp[wv - 1][lane][0] = aA;
        *(float4*)&tmp[wv - 1][lane][4] = aB;
    }
    __syncthreads();
    if (tid < 16) {
#pragma unroll
        for (int w = 0; w < 3; ++w) {
            float4 oA = *(const float4*)&tmp[w][tid][0];
            float4 oB = *(const float4*)&tmp[w][tid][4];
            aA.x += oA.x; aA.y += oA.y; aA.z += oA.z; aA.w += oA.w;
            aB.x += oB.x; aB.y += oB.y; aB.z += oB.z; aB.w += oB.w;
        }
        int cnt = end - beg;
        float inv = (cnt > 0) ? (1.0f / (float)cnt) : 0.f;
        uint4 o;
        o.x = pack_h2(aA.x * inv, aA.y * inv);
        o.y = pack_h2(aA.z * inv, aA.w * inv);
        o.z = pack_h2(aB.x * inv, aB.y * inv);
        o.w = pack_h2(aB.z * inv, aB.w * inv);
        *(uint4*)&mean16[node * D + tid * 8] = o;
    }
}

// ---------------- MFMA fp16 SAGE linear ----------------
// 16 rows x 128 cols per block, 128 threads (2 waves x 4 col-tiles of 16).
__global__ __launch_bounds__(128) void lin_mfma_kernel(
        const __half* __restrict__ A1, const __half* __restrict__ A2,
        const __half* __restrict__ BT1, const __half* __restrict__ BT2,
        const float* __restrict__ bias, __half* __restrict__ out16,
        const float* __restrict__ Wc, const float* __restrict__ bcls,
        float* __restrict__ cls) {
    __shared__ float pl[2][16];
    int r0 = blockIdx.x * 16;
    int w  = (int)threadIdx.x >> 6;   // wave 0..1 -> col half
    int l  = (int)threadIdx.x & 63;
    int lr = l & 15;
    int kg = l >> 4;

    const __half* a1p = A1 + (r0 + lr) * D + kg * 8;
    const __half* a2p = A2 + (r0 + lr) * D + kg * 8;
    f16x8 a1f[4], a2f[4];
#pragma unroll
    for (int ko = 0; ko < 4; ++ko) {
        a1f[ko] = *(const f16x8*)(a1p + ko * 32);
        a2f[ko] = *(const f16x8*)(a2p + ko * 32);
    }

    float p0 = 0.f, p1 = 0.f, p2 = 0.f, p3 = 0.f;

#pragma unroll
    for (int ct = 0; ct < 4; ++ct) {
        int c = w * 64 + ct * 16 + lr;               // output column
        const __half* b1p = BT1 + c * D + kg * 8;
        const __half* b2p = BT2 + c * D + kg * 8;
        f32x4 acc = {0.f, 0.f, 0.f, 0.f};
#pragma unroll
        for (int ko = 0; ko < 4; ++ko)
            acc = MFMA16(a1f[ko], *(const f16x8*)(b1p + ko * 32), acc);
#pragma unroll
        for (int ko = 0; ko < 4; ++ko)
            acc = MFMA16(a2f[ko], *(const f16x8*)(b2p + ko * 32), acc);

        float bcol = bias[c];
        float v0 = fmaxf(acc[0] + bcol, 0.f);
        float v1 = fmaxf(acc[1] + bcol, 0.f);
        float v2 = fmaxf(acc[2] + bcol, 0.f);
        float v3 = fmaxf(acc[3] + bcol, 0.f);
        if (Wc) {
            float wc = Wc[c];
            p0 += v0 * wc; p1 += v1 * wc; p2 += v2 * wc; p3 += v3 * wc;
        } else {
            int rbase = (r0 + kg * 4) * D + c;
            out16[rbase]         = __float2half_rn(v0);
            out16[rbase + D]     = __float2half_rn(v1);
            out16[rbase + 2 * D] = __float2half_rn(v2);
            out16[rbase + 3 * D] = __float2half_rn(v3);
        }
    }

    if (Wc) {
#pragma unroll
        for (int off = 1; off <= 8; off <<= 1) {
            p0 += __shfl_xor(p0, off, 64);
            p1 += __shfl_xor(p1, off, 64);
            p2 += __shfl_xor(p2, off, 64);
            p3 += __shfl_xor(p3, off, 64);
        }
        if (lr == 0) {
            pl[w][kg * 4 + 0] = p0;
            pl[w][kg * 4 + 1] = p1;
            pl[w][kg * 4 + 2] = p2;
            pl[w][kg * 4 + 3] = p3;
        }
        __syncthreads();
        if (threadIdx.x < 16) {
            float s = pl[0][threadIdx.x] + pl[1][threadIdx.x] + bcls[0];
            cls[r0 + threadIdx.x] = 1.0f / (1.0f + expf(-s));
        }
    }
}

extern "C" void kernel_launch(void* const* d_in, const int* in_sizes, int n_in,
                              void* d_out, int out_size, void* d_ws, size_t ws_size,
                              hipStream_t stream) {
    const float* x   = (const float*)d_in[0];
    const int* eidx  = (const int*)d_in[1];
    int E = in_sizes[1] / 2;
    const int* src = eidx;
    const int* dst = eidx + E;
    const float* W1l = (const float*)d_in[2];
    const float* b1  = (const float*)d_in[3];
    const float* W1r = (const float*)d_in[4];
    const float* W2l = (const float*)d_in[5];
    const float* b2  = (const float*)d_in[6];
    const float* W2r = (const float*)d_in[7];
    const float* W3l = (const float*)d_in[8];
    const float* b3  = (const float*)d_in[9];
    const float* W3r = (const float*)d_in[10];
    const float* Wc  = (const float*)d_in[11];
    const float* bc  = (const float*)d_in[12];
    float* out = (float*)d_out;

    // workspace carve-up
    char* p = (char*)d_ws;
    int* degN      = (int*)p;   p += (size_t)NCOPY * N_NODES * 4;   // 640000
    int* baseN     = (int*)p;   p += (size_t)NCOPY * N_NODES * 4;
    int* offsets   = (int*)p;   p += 40960;
    int* tot       = (int*)p;   p += 40960;
    int* csr_src   = (int*)p;   p += (size_t)E * 4;
    __half* mean16 = (__half*)p; p += (size_t)N_NODES * D * 2;
    __half* xm     = (__half*)p; p += (size_t)N_NODES * D * 2;
    __half* m1     = (__half*)p; p += (size_t)N_NODES * D * 2;
    __half* m2     = (__half*)p; p += (size_t)N_NODES * D * 2;
    __half* WT     = (__half*)p; p += (size_t)6 * D * D * 2;

    int n8  = N_NODES * D / 8;                 // 160000
    int nz16 = (NCOPY * N_NODES * 4) / 16;     // 40000
    int nwt = 6 * D * D;                       // 98304
    prep_kernel<<<(n8 + 255) / 256, 256, 0, stream>>>(
        x, xm, W1l, W1r, W2l, W2r, W3l, W3r, WT, (uint4*)degN, n8, nz16, nwt);

    int eb = (E + 255) / 256;
    int nb = (N_NODES + 255) / 256;
    deg_kernel<<<eb, 256, 0, stream>>>(dst, E, degN);
    sumdeg_kernel<<<nb, 256, 0, stream>>>(degN, tot, N_NODES);
    scan_kernel<<<1, 1024, 0, stream>>>(tot, offsets, N_NODES);
    baseN_kernel<<<nb, 256, 0, stream>>>(degN, offsets, baseN, N_NODES);
    scatter_kernel<<<eb, 256, 0, stream>>>(src, dst, E, baseN, csr_src);

    int lin_grid = N_NODES / 16;   // 625, exact

    // layer 1
    aggregate_kernel<<<N_NODES, 256, 0, stream>>>(xm, offsets, csr_src, mean16);
    lin_mfma_kernel<<<lin_grid, 128, 0, stream>>>(
        mean16, xm, WT, WT + D * D, b1, m1,
        (const float*)nullptr, (const float*)nullptr, (float*)nullptr);
    // layer 2
    aggregate_kernel<<<N_NODES, 256, 0, stream>>>(m1, offsets, csr_src, mean16);
    lin_mfma_kernel<<<lin_grid, 128, 0, stream>>>(
        mean16, m1, WT + 2 * D * D, WT + 3 * D * D, b2, m2,
        (const float*)nullptr, (const float*)nullptr, (float*)nullptr);
    // layer 3 + classifier
    aggregate_kernel<<<N_NODES, 256, 0, stream>>>(m2, offsets, csr_src, mean16);
    lin_mfma_kernel<<<lin_grid, 128, 0, stream>>>(
        mean16, m2, WT + 4 * D * D, WT + 5 * D * D, b3, (__half*)nullptr,
        Wc, bc, out);
}

// Round 14
// 129.365 us; speedup vs baseline: 1.1607x; 1.1607x over previous
//
#include <hip/hip_runtime.h>
#include <hip/hip_fp16.h>
#include <math.h>

#define N_NODES 10000
#define D 128
#define NCOPY 16

typedef unsigned int uint_t;
typedef __attribute__((ext_vector_type(8))) _Float16 f16x8;
typedef __attribute__((ext_vector_type(4))) float f32x4;

#define MFMA16(a, b, c) __builtin_amdgcn_mfma_f32_16x16x32_f16((a), (b), (c), 0, 0, 0)

__device__ inline uint_t pack_h2(float lo, float hi) {
    __half2 h = __floats2half2_rn(lo, hi);
    return *(uint_t*)&h;
}
__device__ inline void acc_h8(uint4 v, float4& aA, float4& aB) {
    float2 f;
    f = __half22float2(*(__half2*)&v.x); aA.x += f.x; aA.y += f.y;
    f = __half22float2(*(__half2*)&v.y); aA.z += f.x; aA.w += f.y;
    f = __half22float2(*(__half2*)&v.z); aB.x += f.x; aB.y += f.y;
    f = __half22float2(*(__half2*)&v.w); aB.z += f.x; aB.w += f.y;
}

// ---------------- prep: zero deg + fp16 mirror of x + W^T fp16 ----------------
__global__ void prep_kernel(const float* __restrict__ x, __half* __restrict__ xm,
                            const float* __restrict__ W1l, const float* __restrict__ W1r,
                            const float* __restrict__ W2l, const float* __restrict__ W2r,
                            const float* __restrict__ W3l, const float* __restrict__ W3r,
                            __half* __restrict__ WT,
                            uint4* __restrict__ degz, int n8, int nz16, int nwt) {
    int i = blockIdx.x * blockDim.x + threadIdx.x;
    if (i < nz16) degz[i] = make_uint4(0u, 0u, 0u, 0u);
    if (i < n8) {
        const float4* p = (const float4*)x + (size_t)i * 2;
        float4 a = p[0], b = p[1];
        uint4 o;
        o.x = pack_h2(a.x, a.y); o.y = pack_h2(a.z, a.w);
        o.z = pack_h2(b.x, b.y); o.w = pack_h2(b.z, b.w);
        ((uint4*)xm)[i] = o;
    }
    if (i < nwt) {
        int m = i >> 14, idx = i & 16383;
        int n = idx >> 7, k = idx & 127;
        const float* Wm = (m == 0) ? W1l : (m == 1) ? W1r : (m == 2) ? W2l
                        : (m == 3) ? W2r : (m == 4) ? W3l : W3r;
        WT[i] = __float2half_rn(Wm[k * D + n]);   // WT[m][n][k] = W[k][n]
    }
}

// ---------------- CSR build ----------------
// pass 1: replicated histogram + per-edge rank; pos write is coalesced and
// independent of the atomic return's value (no addr dependency -> no serialization).
__global__ void rank_kernel(const int* __restrict__ dst, int E,
                            int* __restrict__ degN, int* __restrict__ pos) {
    int i = blockIdx.x * blockDim.x + threadIdx.x;
    if (i < E) {
        int c = blockIdx.x & (NCOPY - 1);
        pos[i] = atomicAdd(&degN[c * N_NODES + dst[i]], 1);
    }
}

__global__ void sumdeg_kernel(const int* __restrict__ degN, int* __restrict__ tot, int n) {
    int i = blockIdx.x * blockDim.x + threadIdx.x;
    if (i < n) {
        int s = 0;
#pragma unroll
        for (int c = 0; c < NCOPY; ++c) s += degN[c * N_NODES + i];
        tot[i] = s;
    }
}

// single-block scan with LDS-staged coalesced IO: tot[0..n) -> offsets[0..n]
#define SCAN_PER 10
#define SCAN_N 10240
__global__ __launch_bounds__(1024) void scan_kernel(const int* __restrict__ tot,
                                                    int* __restrict__ offsets, int n) {
    __shared__ int buf[SCAN_N];
    __shared__ int wsum[16];
    __shared__ int wpre[16];
    int tid = threadIdx.x;
    int lane = tid & 63, wid = tid >> 6;
#pragma unroll
    for (int q = 0; q < SCAN_PER; ++q) {
        int idx = q * 1024 + tid;
        buf[idx] = (idx < n) ? tot[idx] : 0;
    }
    __syncthreads();
    int base = tid * SCAN_PER;
    int loc[SCAN_PER];
    int s = 0;
#pragma unroll
    for (int q = 0; q < SCAN_PER; ++q) {
        s += buf[base + q];
        loc[q] = s;
    }
    int mysum = s;
#pragma unroll
    for (int off = 1; off < 64; off <<= 1) {
        int t = __shfl_up(s, off, 64);
        if (lane >= off) s += t;
    }
    if (lane == 63) wsum[wid] = s;
    __syncthreads();
    if (wid == 0 && lane < 16) {
        int v = wsum[lane];
        int ss = v;
#pragma unroll
        for (int off = 1; off < 16; off <<= 1) {
            int t = __shfl_up(ss, off, 16);
            if ((lane & 15) >= off) ss += t;
        }
        wpre[lane] = ss - v;
    }
    __syncthreads();
    int thread_excl = wpre[wid] + (s - mysum);
#pragma unroll
    for (int q = 0; q < SCAN_PER; ++q) buf[base + q] = thread_excl + loc[q];
    __syncthreads();
#pragma unroll
    for (int q = 0; q < SCAN_PER; ++q) {
        int idx = q * 1024 + tid;
        if (idx < n) offsets[idx + 1] = buf[idx];
    }
    if (tid == 0) offsets[0] = 0;
}

__global__ void baseN_kernel(const int* __restrict__ degN, const int* __restrict__ offsets,
                             int* __restrict__ baseN, int n) {
    int i = blockIdx.x * blockDim.x + threadIdx.x;
    if (i < n) {
        int run = offsets[i];
#pragma unroll
        for (int c = 0; c < NCOPY; ++c) {
            baseN[c * N_NODES + i] = run;
            run += degN[c * N_NODES + i];
        }
    }
}

// pass 2: pure streaming write, no atomics; addresses from plain loads only.
__global__ void csr_write_kernel(const int* __restrict__ src, const int* __restrict__ dst,
                                 const int* __restrict__ pos, int E,
                                 const int* __restrict__ baseN, int* __restrict__ csr_src) {
    int i = blockIdx.x * blockDim.x + threadIdx.x;
    if (i < E) {
        int c = (i >> 8) & (NCOPY - 1);  // matches rank_kernel (256 thr/block)
        csr_src[baseN[c * N_NODES + dst[i]] + pos[i]] = src[i];
    }
}

// ---------------- aggregation (segment mean, fp16 gather -> fp16 mean) ----------------
// 256 threads per node: 16 edge-groups x 16 lanes; lane covers 8 features (16B).
// Edge loop unrolled x2 with independent accumulators for ILP.
__global__ __launch_bounds__(256) void aggregate_kernel(const __half* __restrict__ h16,
                                                        const int* __restrict__ offsets,
                                                        const int* __restrict__ csr_src,
                                                        __half* __restrict__ mean16) {
    __shared__ float tmp[3][16][8];
    int node = blockIdx.x;
    int tid = threadIdx.x;
    int g = tid >> 4;          // 0..15 edge group
    int fl = tid & 15;         // feature block (8 fp16 = 16B)
    int beg = offsets[node], end = offsets[node + 1];
    float4 aA = make_float4(0.f, 0.f, 0.f, 0.f);
    float4 aB = make_float4(0.f, 0.f, 0.f, 0.f);
    float4 cA = make_float4(0.f, 0.f, 0.f, 0.f);
    float4 cB = make_float4(0.f, 0.f, 0.f, 0.f);
    int e = beg + g;
    for (; e + 16 < end; e += 32) {
        int s0 = csr_src[e];
        int s1 = csr_src[e + 16];
        uint4 v0 = *(const uint4*)&h16[s0 * D + fl * 8];
        uint4 v1 = *(const uint4*)&h16[s1 * D + fl * 8];
        acc_h8(v0, aA, aB);
        acc_h8(v1, cA, cB);
    }
    if (e < end) {
        int s0 = csr_src[e];
        uint4 v0 = *(const uint4*)&h16[s0 * D + fl * 8];
        acc_h8(v0, aA, aB);
    }
    aA.x += cA.x; aA.y += cA.y; aA.z += cA.z; aA.w += cA.w;
    aB.x += cB.x; aB.y += cB.y; aB.z += cB.z; aB.w += cB.w;
    aA.x += __shfl_xor(aA.x, 16, 64); aA.y += __shfl_xor(aA.y, 16, 64);
    aA.z += __shfl_xor(aA.z, 16, 64); aA.w += __shfl_xor(aA.w, 16, 64);
    aB.x += __shfl_xor(aB.x, 16, 64); aB.y += __shfl_xor(aB.y, 16, 64);
    aB.z += __shfl_xor(aB.z, 16, 64); aB.w += __shfl_xor(aB.w, 16, 64);
    aA.x += __shfl_xor(aA.x, 32, 64); aA.y += __shfl_xor(aA.y, 32, 64);
    aA.z += __shfl_xor(aA.z, 32, 64); aA.w += __shfl_xor(aA.w, 32, 64);
    aB.x += __shfl_xor(aB.x, 32, 64); aB.y += __shfl_xor(aB.y, 32, 64);
    aB.z += __shfl_xor(aB.z, 32, 64); aB.w += __shfl_xor(aB.w, 32, 64);
    int wv = tid >> 6;
    int lane = tid & 63;
    if (wv > 0 && lane < 16) {
        *(float4*)&tmp[wv - 1][lane][0] = aA;
        *(float4*)&tmp[wv - 1][lane][4] = aB;
    }
    __syncthreads();
    if (tid < 16) {
#pragma unroll
        for (int w = 0; w < 3; ++w) {
            float4 oA = *(const float4*)&tmp[w][tid][0];
            float4 oB = *(const float4*)&tmp[w][tid][4];
            aA.x += oA.x; aA.y += oA.y; aA.z += oA.z; aA.w += oA.w;
            aB.x += oB.x; aB.y += oB.y; aB.z += oB.z; aB.w += oB.w;
        }
        int cnt = end - beg;
        float inv = (cnt > 0) ? (1.0f / (float)cnt) : 0.f;
        uint4 o;
        o.x = pack_h2(aA.x * inv, aA.y * inv);
        o.y = pack_h2(aA.z * inv, aA.w * inv);
        o.z = pack_h2(aB.x * inv, aB.y * inv);
        o.w = pack_h2(aB.z * inv, aB.w * inv);
        *(uint4*)&mean16[node * D + tid * 8] = o;
    }
}

// ---------------- MFMA fp16 SAGE linear ----------------
// 16 rows x 128 cols per block, 128 threads (2 waves x 4 col-tiles of 16).
__global__ __launch_bounds__(128) void lin_mfma_kernel(
        const __half* __restrict__ A1, const __half* __restrict__ A2,
        const __half* __restrict__ BT1, const __half* __restrict__ BT2,
        const float* __restrict__ bias, __half* __restrict__ out16,
        const float* __restrict__ Wc, const float* __restrict__ bcls,
        float* __restrict__ cls) {
    __shared__ float pl[2][16];
    int r0 = blockIdx.x * 16;
    int w  = (int)threadIdx.x >> 6;   // wave 0..1 -> col half
    int l  = (int)threadIdx.x & 63;
    int lr = l & 15;
    int kg = l >> 4;

    const __half* a1p = A1 + (r0 + lr) * D + kg * 8;
    const __half* a2p = A2 + (r0 + lr) * D + kg * 8;
    f16x8 a1f[4], a2f[4];
#pragma unroll
    for (int ko = 0; ko < 4; ++ko) {
        a1f[ko] = *(const f16x8*)(a1p + ko * 32);
        a2f[ko] = *(const f16x8*)(a2p + ko * 32);
    }

    float p0 = 0.f, p1 = 0.f, p2 = 0.f, p3 = 0.f;

#pragma unroll
    for (int ct = 0; ct < 4; ++ct) {
        int c = w * 64 + ct * 16 + lr;               // output column
        const __half* b1p = BT1 + c * D + kg * 8;
        const __half* b2p = BT2 + c * D + kg * 8;
        f32x4 acc = {0.f, 0.f, 0.f, 0.f};
#pragma unroll
        for (int ko = 0; ko < 4; ++ko)
            acc = MFMA16(a1f[ko], *(const f16x8*)(b1p + ko * 32), acc);
#pragma unroll
        for (int ko = 0; ko < 4; ++ko)
            acc = MFMA16(a2f[ko], *(const f16x8*)(b2p + ko * 32), acc);

        float bcol = bias[c];
        float v0 = fmaxf(acc[0] + bcol, 0.f);
        float v1 = fmaxf(acc[1] + bcol, 0.f);
        float v2 = fmaxf(acc[2] + bcol, 0.f);
        float v3 = fmaxf(acc[3] + bcol, 0.f);
        if (Wc) {
            float wc = Wc[c];
            p0 += v0 * wc; p1 += v1 * wc; p2 += v2 * wc; p3 += v3 * wc;
        } else {
            int rbase = (r0 + kg * 4) * D + c;
            out16[rbase]         = __float2half_rn(v0);
            out16[rbase + D]     = __float2half_rn(v1);
            out16[rbase + 2 * D] = __float2half_rn(v2);
            out16[rbase + 3 * D] = __float2half_rn(v3);
        }
    }

    if (Wc) {
#pragma unroll
        for (int off = 1; off <= 8; off <<= 1) {
            p0 += __shfl_xor(p0, off, 64);
            p1 += __shfl_xor(p1, off, 64);
            p2 += __shfl_xor(p2, off, 64);
            p3 += __shfl_xor(p3, off, 64);
        }
        if (lr == 0) {
            pl[w][kg * 4 + 0] = p0;
            pl[w][kg * 4 + 1] = p1;
            pl[w][kg * 4 + 2] = p2;
            pl[w][kg * 4 + 3] = p3;
        }
        __syncthreads();
        if (threadIdx.x < 16) {
            float s = pl[0][threadIdx.x] + pl[1][threadIdx.x] + bcls[0];
            cls[r0 + threadIdx.x] = 1.0f / (1.0f + expf(-s));
        }
    }
}

extern "C" void kernel_launch(void* const* d_in, const int* in_sizes, int n_in,
                              void* d_out, int out_size, void* d_ws, size_t ws_size,
                              hipStream_t stream) {
    const float* x   = (const float*)d_in[0];
    const int* eidx  = (const int*)d_in[1];
    int E = in_sizes[1] / 2;
    const int* src = eidx;
    const int* dst = eidx + E;
    const float* W1l = (const float*)d_in[2];
    const float* b1  = (const float*)d_in[3];
    const float* W1r = (const float*)d_in[4];
    const float* W2l = (const float*)d_in[5];
    const float* b2  = (const float*)d_in[6];
    const float* W2r = (const float*)d_in[7];
    const float* W3l = (const float*)d_in[8];
    const float* b3  = (const float*)d_in[9];
    const float* W3r = (const float*)d_in[10];
    const float* Wc  = (const float*)d_in[11];
    const float* bc  = (const float*)d_in[12];
    float* out = (float*)d_out;

    // workspace carve-up
    char* p = (char*)d_ws;
    int* degN      = (int*)p;   p += (size_t)NCOPY * N_NODES * 4;   // 640000
    int* baseN     = (int*)p;   p += (size_t)NCOPY * N_NODES * 4;
    int* offsets   = (int*)p;   p += 40960;
    int* tot       = (int*)p;   p += 40960;
    int* csr_src   = (int*)p;   p += (size_t)E * 4;
    int* pos       = (int*)p;   p += (size_t)E * 4;
    __half* mean16 = (__half*)p; p += (size_t)N_NODES * D * 2;
    __half* xm     = (__half*)p; p += (size_t)N_NODES * D * 2;
    __half* m1     = (__half*)p; p += (size_t)N_NODES * D * 2;
    __half* m2     = (__half*)p; p += (size_t)N_NODES * D * 2;
    __half* WT     = (__half*)p; p += (size_t)6 * D * D * 2;

    int n8  = N_NODES * D / 8;                 // 160000
    int nz16 = (NCOPY * N_NODES * 4) / 16;     // 40000
    int nwt = 6 * D * D;                       // 98304
    prep_kernel<<<(n8 + 255) / 256, 256, 0, stream>>>(
        x, xm, W1l, W1r, W2l, W2r, W3l, W3r, WT, (uint4*)degN, n8, nz16, nwt);

    int eb = (E + 255) / 256;
    int nb = (N_NODES + 255) / 256;
    rank_kernel<<<eb, 256, 0, stream>>>(dst, E, degN, pos);
    sumdeg_kernel<<<nb, 256, 0, stream>>>(degN, tot, N_NODES);
    scan_kernel<<<1, 1024, 0, stream>>>(tot, offsets, N_NODES);
    baseN_kernel<<<nb, 256, 0, stream>>>(degN, offsets, baseN, N_NODES);
    csr_write_kernel<<<eb, 256, 0, stream>>>(src, dst, pos, E, baseN, csr_src);

    int lin_grid = N_NODES / 16;   // 625, exact

    // layer 1
    aggregate_kernel<<<N_NODES, 256, 0, stream>>>(xm, offsets, csr_src, mean16);
    lin_mfma_kernel<<<lin_grid, 128, 0, stream>>>(
        mean16, xm, WT, WT + D * D, b1, m1,
        (const float*)nullptr, (const float*)nullptr, (float*)nullptr);
    // layer 2
    aggregate_kernel<<<N_NODES, 256, 0, stream>>>(m1, offsets, csr_src, mean16);
    lin_mfma_kernel<<<lin_grid, 128, 0, stream>>>(
        mean16, m1, WT + 2 * D * D, WT + 3 * D * D, b2, m2,
        (const float*)nullptr, (const float*)nullptr, (float*)nullptr);
    // layer 3 + classifier
    aggregate_kernel<<<N_NODES, 256, 0, stream>>>(m2, offsets, csr_src, mean16);
    lin_mfma_kernel<<<lin_grid, 128, 0, stream>>>(
        mean16, m2, WT + 4 * D * D, WT + 5 * D * D, b3, (__half*)nullptr,
        Wc, bc, out);
}